// Round 11
// baseline (387.468 us; speedup 1.0000x reference)
//
#include <hip/hip_runtime.h>
#include <stdint.h>

#define B_ROWS 8192
#define DIM 4096
#define E_CODES 512
#define MARGIN 16.0f

typedef __attribute__((ext_vector_type(8))) short short8;
typedef __attribute__((ext_vector_type(4))) float floatx4;
typedef __attribute__((ext_vector_type(4), aligned(4))) float f4u;  // unaligned-ok float4
typedef unsigned short ushort_t;

// ---- workspace layout (float units) ----
#define WS_SCORES 0                       // final scores: 8192*512 floats
#define WS_ENORM  4194304                 // 512 floats: ||e||^2 for k_gemm, then ZEROED and
                                          // reused as 512 loss partial-sum slots for k_fused
#define WS_COUNTS 4194816                 // 512 ints

// ---- output layout (float units) ----
#define O_LOSS 0
#define O_Q    1
#define O_PERP 33554433
#define O_ENC  33554434
// scratch carved out of the Q region (fully overwritten by k_fused afterwards):
#define O_CBBF  20971528   // bf16 CB (swizzled): [20971528, 22020104)

#define AS1 __attribute__((address_space(1)))
#define AS3 __attribute__((address_space(3)))

__device__ __forceinline__ void gld_lds16(const void* g, void* l) {
    // async global->LDS, 16B per lane; LDS dest = wave-uniform base + lane*16
    __builtin_amdgcn_global_load_lds((AS1 const void*)g, (AS3 void*)l, 16, 0, 0);
}

// pack two fp32 into (bf16(hi)<<16)|bf16(lo) by truncation — one v_perm_b32
__device__ inline uint32_t pk2(float hi, float lo) {
    return __builtin_amdgcn_perm(__float_as_uint(hi), __float_as_uint(lo), 0x07060302u);
}

// ---------------- codebook norms + bf16 pack (swizzled) ----------------
// Pack swizzle: within each 64-elem K-block, 16B-chunk g&7 of row e stored at ((g&7)^(e&7)).
__global__ __launch_bounds__(64) void k_enorm(const float* __restrict__ cb, float* __restrict__ enorm,
                                              ushort_t* __restrict__ cbbf) {
    const int e = blockIdx.x;
    const int lane = threadIdx.x;
    const float4* c4 = (const float4*)(cb + (size_t)e * DIM);
    float p = 0.f;
#pragma unroll
    for (int j = 0; j < 16; j++) {
        float4 v = c4[j * 64 + lane];
        p = fmaf(v.x, v.x, fmaf(v.y, v.y, fmaf(v.z, v.z, fmaf(v.w, v.w, p))));
    }
    for (int off = 32; off; off >>= 1) p += __shfl_down(p, off);
    if (lane == 0) enorm[e] = p;
    // pack this row (reads are L1-hot from the norm pass)
#pragma unroll
    for (int k = 0; k < 8; k++) {
        const int g = k * 64 + lane;
        const int gs = (g & ~7) | ((g & 7) ^ (e & 7));
        float4 v0 = c4[2 * g], v1 = c4[2 * g + 1];
        *(uint4*)(cbbf + (size_t)e * DIM + gs * 8) =
            make_uint4(pk2(v0.y, v0.x), pk2(v0.w, v0.z), pk2(v1.y, v1.x), pk2(v1.w, v1.z));
    }
}

// ---------------- bf16 score GEMM: BM=64, BN=128, BK=64, counted-vmcnt 2-deep pipeline ------------
// A staged DIRECTLY from fp32 X: global loads -> pk2 pack -> swizzled ds_write (reg-staged,
// named rA/rB sets rotated statically). B staged via global_load_lds from pre-swizzled cbbf.
// 8 VMEM ops/wave/iter (4 gld_lds B + 4 A loads) -> vmcnt(8) retires exactly the previous
// iteration's batch. Compute(b0) needs only >=2-iter-old data, so it runs BEFORE the wait.
__global__ __launch_bounds__(256, 2) void k_gemm(const float* __restrict__ X, const ushort_t* __restrict__ cbbf,
                                                 const float* __restrict__ enorm, float* __restrict__ scores) {
    __shared__ __align__(16) ushort_t As[3 * 64 * 64];    // 3 x 8 KiB
    __shared__ __align__(16) ushort_t Bs[3 * 128 * 64];   // 3 x 16 KiB
    const int bid = blockIdx.x;
    const int bn = bid & 3;
    const int bm = bid >> 2;
    const int tid = threadIdx.x;
    const int lane = tid & 63;
    const int w = tid >> 6;
    const int wr = w >> 1, wc = w & 1;
    const int m16 = lane & 15, q4 = lane >> 4;

    // B staging (unchanged): lane l covers (row l>>3, 16B chunk l&7) of an 8-row stripe
    const int srow = lane >> 3;
    const int scol = (lane & 7) * 8;
    const ushort_t* bx = cbbf + (size_t)(bn * 128 + w * 8 + srow) * DIM + scol;

    // A reg-staging: lane l covers row w*16 + (l>>2), fp32 cols (l&3)*16 .. +16 of the K-tile
    const int arow = w * 16 + (lane >> 2);
    const float4* axf = (const float4*)(X + (size_t)(bm * 64 + arow) * DIM + (lane & 3) * 16);
    const int c0 = (lane & 3) * 2;
    const int sfx = arow & 7;
    const int apos1 = ((c0) ^ sfx) * 8;
    const int apos2 = ((c0 + 1) ^ sfx) * 8;

    floatx4 acc[2][4];
#pragma unroll
    for (int i = 0; i < 2; i++)
#pragma unroll
        for (int j = 0; j < 4; j++) acc[i][j] = (floatx4){0.f, 0.f, 0.f, 0.f};

    const int kx = (m16 & 7) * 8;  // frag-read XOR key (ushort units); matches arow&7 (=m16&7)

#define STAGE_B(BUF, KT)                                                                    \
    {                                                                                       \
        ushort_t* bsd = &Bs[(BUF) * 8192];                                                  \
        _Pragma("unroll")                                                                   \
        for (int j = 0; j < 4; j++)                                                         \
            gld_lds16(bx + (size_t)j * 32 * DIM + (KT), bsd + (j * 32 + w * 8) * 64);       \
    }
#define LOADA(P, KT)                                                                        \
    { const float4* s_ = axf + ((KT) >> 2); P##0 = s_[0]; P##1 = s_[1]; P##2 = s_[2]; P##3 = s_[3]; }
#define PACKA(P, BUF)                                                                       \
    {                                                                                       \
        *(uint4*)(&As[(BUF) * 4096 + arow * 64 + apos1]) =                                  \
            make_uint4(pk2((P##0).y, (P##0).x), pk2((P##0).w, (P##0).z),                    \
                       pk2((P##1).y, (P##1).x), pk2((P##1).w, (P##1).z));                   \
        *(uint4*)(&As[(BUF) * 4096 + arow * 64 + apos2]) =                                  \
            make_uint4(pk2((P##2).y, (P##2).x), pk2((P##2).w, (P##2).z),                    \
                       pk2((P##3).y, (P##3).x), pk2((P##3).w, (P##3).z));                   \
    }
#define COMPUTE(BUF)                                                                        \
    {                                                                                       \
        const ushort_t* Ab = &As[(BUF) * 4096];                                             \
        const ushort_t* Bb = &Bs[(BUF) * 8192];                                             \
        _Pragma("unroll")                                                                   \
        for (int kk = 0; kk < 2; kk++) {                                                    \
            short8 a[2], b[4];                                                              \
            _Pragma("unroll")                                                               \
            for (int i = 0; i < 2; i++)                                                     \
                a[i] = *(const short8*)(&Ab[(wr * 32 + i * 16 + m16) * 64 + ((kk * 32 + q4 * 8) ^ kx)]); \
            _Pragma("unroll")                                                               \
            for (int j = 0; j < 4; j++)                                                     \
                b[j] = *(const short8*)(&Bb[(wc * 64 + j * 16 + m16) * 64 + ((kk * 32 + q4 * 8) ^ kx)]); \
            _Pragma("unroll")                                                               \
            for (int i = 0; i < 2; i++)                                                     \
                _Pragma("unroll")                                                           \
                for (int j = 0; j < 4; j++)                                                 \
                    acc[i][j] = __builtin_amdgcn_mfma_f32_16x16x32_bf16(a[i], b[j], acc[i][j], 0, 0, 0); \
        }                                                                                   \
    }
#define TOPBAR                                                                              \
    asm volatile("s_waitcnt lgkmcnt(0)" ::: "memory");                                      \
    __builtin_amdgcn_s_barrier();                                                           \
    __builtin_amdgcn_sched_barrier(0);
#define ROT { const int tmp_ = b0; b0 = b1; b1 = b2; b2 = tmp_; }

    float4 rA0, rA1, rA2, rA3, rB0, rB1, rB2, rB3;

    // prologue: tiles 0,1 in flight; pack tile0 (own-wave writes; barrier at loop top publishes)
    STAGE_B(0, 0)   LOADA(rA, 0)
    STAGE_B(1, 64)  LOADA(rB, 64)
    asm volatile("s_waitcnt vmcnt(8)" ::: "memory");   // batch 0 retired
    PACKA(rA, 0)
    int b0 = 0, b1 = 1, b2 = 2;

    for (int t = 0; t < 62; t += 2) {
        // sub-iter t (computes tile t, packs tile t+1 from rB, loads tile t+2 into rA)
        TOPBAR
        STAGE_B(b2, (t + 2) * 64)  LOADA(rA, (t + 2) * 64)
        COMPUTE(b0)
        asm volatile("s_waitcnt vmcnt(8)" ::: "memory");   // previous batch retired -> rB valid
        PACKA(rB, b1)
        __builtin_amdgcn_sched_barrier(0);
        ROT
        // sub-iter t+1 (computes t+1, packs t+2 from rA, loads t+3 into rB)
        TOPBAR
        STAGE_B(b2, (t + 3) * 64)  LOADA(rB, (t + 3) * 64)
        COMPUTE(b0)
        asm volatile("s_waitcnt vmcnt(8)" ::: "memory");
        PACKA(rA, b1)
        __builtin_amdgcn_sched_barrier(0);
        ROT
    }
    // t = 62: compute 62, pack tile 63 from rB (loaded at t=61)
    TOPBAR
    COMPUTE(b0)
    asm volatile("s_waitcnt vmcnt(0)" ::: "memory");
    PACKA(rB, b1)
    __builtin_amdgcn_sched_barrier(0);
    ROT
    // t = 63
    TOPBAR
    COMPUTE(b0)
#undef STAGE_B
#undef LOADA
#undef PACKA
#undef COMPUTE
#undef TOPBAR
#undef ROT

    // epilogue: score = ||e||^2 - 2*dot ; C/D layout: col=lane&15, row=(lane>>4)*4+rr
#pragma unroll
    for (int j = 0; j < 4; j++) {
        const int col = bn * 128 + wc * 64 + j * 16 + m16;
        const float en = enorm[col];
#pragma unroll
        for (int i = 0; i < 2; i++) {
            const int row0 = bm * 64 + wr * 32 + i * 16 + q4 * 4;
#pragma unroll
            for (int rr = 0; rr < 4; rr++)
                scores[(size_t)(row0 + rr) * E_CODES + col] = fmaf(-2.0f, acc[i][j][rr], en);
        }
    }
}

// ---------------- fused: argmin + (rare) exact refine + quantize + one-hot + loss ----------------
// X-row prefetch issued BEFORE the argmin phase and pinned with sched_barrier(0) (round-8 win).
__global__ __launch_bounds__(256) void k_fused(const float* __restrict__ X, const float* __restrict__ CB,
                                               const float* __restrict__ scores,
                                               int* __restrict__ counts, float* __restrict__ lossp,
                                               float* __restrict__ out) {
    __shared__ float lred[4];
    const int tid = threadIdx.x;
    const int lane = tid & 63, w = tid >> 6;
    const int row = blockIdx.x * 4 + w;

    // phase 0a: issue score loads
    const float* sr = scores + (size_t)row * E_CODES;
    float s[8];
#pragma unroll
    for (int g = 0; g < 8; g++) s[g] = sr[g * 64 + lane];
    __builtin_amdgcn_sched_barrier(0);   // scores issued first (argmin waits only on these)

    // phase 0b: issue the full X row as 16 named float4 loads — independent of argmin
    const float4* xr4 = (const float4*)(X + (size_t)row * DIM);
#define LDX(K) float4 x##K = xr4[(K) * 64 + lane];
    LDX(0) LDX(1) LDX(2) LDX(3) LDX(4) LDX(5) LDX(6) LDX(7)
    LDX(8) LDX(9) LDX(10) LDX(11) LDX(12) LDX(13) LDX(14) LDX(15)
#undef LDX
    __builtin_amdgcn_sched_barrier(0);   // pin: X loads may NOT sink below this point

    // phase 1: wave argmin (approx scores), tie -> lower index
    float mv = s[0]; int mi = lane;
#pragma unroll
    for (int g = 1; g < 8; g++) { if (s[g] < mv) { mv = s[g]; mi = g * 64 + lane; } }
    for (int off = 32; off; off >>= 1) {
        float ov = __shfl_xor(mv, off); int oi = __shfl_xor(mi, off);
        if (ov < mv || (ov == mv && oi < mi)) { mv = ov; mi = oi; }
    }
    const float thr = mv + MARGIN;

    unsigned long long m0 = __ballot(s[0] <= thr), m1 = __ballot(s[1] <= thr);
    unsigned long long m2 = __ballot(s[2] <= thr), m3 = __ballot(s[3] <= thr);
    unsigned long long m4 = __ballot(s[4] <= thr), m5 = __ballot(s[5] <= thr);
    unsigned long long m6 = __ballot(s[6] <= thr), m7 = __ballot(s[7] <= thr);
    const int ncand = __popcll(m0) + __popcll(m1) + __popcll(m2) + __popcll(m3) +
                      __popcll(m4) + __popcll(m5) + __popcll(m6) + __popcll(m7);

    int beste = mi;  // unique candidate == approx argmin

    if (ncand > 1) {
        // exact fp32 refine over margin candidates; butterfly sums bit-identical on all lanes
        float bestd = 3.0e38f; beste = 1 << 30;
#define REFINE_GROUP(MG, G)                                                                 \
        {                                                                                   \
            unsigned long long mask = (MG);                                                 \
            while (mask) {                                                                  \
                const int b = __builtin_ctzll(mask); mask &= mask - 1;                      \
                const int e = (G) * 64 + b;                                                 \
                const float4* cr4 = (const float4*)(CB + (size_t)e * DIM);                  \
                float p = 0.f;                                                              \
                _Pragma("unroll")                                                           \
                for (int i = 0; i < 16; i++) {                                              \
                    float4 c = cr4[i * 64 + lane];                                          \
                    float4 x = xr4[i * 64 + lane];                                          \
                    float dx = x.x - c.x, dy = x.y - c.y, dz = x.z - c.z, dw = x.w - c.w;   \
                    p = fmaf(dx, dx, fmaf(dy, dy, fmaf(dz, dz, fmaf(dw, dw, p))));          \
                }                                                                           \
                for (int off = 32; off; off >>= 1) p += __shfl_xor(p, off);                 \
                if (p < bestd || (p == bestd && e < beste)) { bestd = p; beste = e; }       \
            }                                                                               \
        }
        REFINE_GROUP(m0, 0) REFINE_GROUP(m1, 1) REFINE_GROUP(m2, 2) REFINE_GROUP(m3, 3)
        REFINE_GROUP(m4, 4) REFINE_GROUP(m5, 5) REFINE_GROUP(m6, 6) REFINE_GROUP(m7, 7)
#undef REFINE_GROUP
    }

    // phase 2: quantized_st = x + (q - x); loss fma-nest i=0..15 + butterfly (bitwise as before).
    const float4* cq4 = (const float4*)(CB + (size_t)beste * DIM);
    f4u* oq4 = (f4u*)(out + O_Q + (size_t)row * DIM);   // out+1 is only 4B-aligned

#define LDQ(K) float4 q##K = cq4[(K) * 64 + lane];
    LDQ(0) LDQ(1) LDQ(2) LDQ(3) LDQ(4) LDQ(5) LDQ(6) LDQ(7)
    LDQ(8) LDQ(9) LDQ(10) LDQ(11) LDQ(12) LDQ(13) LDQ(14) LDQ(15)
#undef LDQ
    float p = 0.f;
#define ST(K)                                                                               \
    {                                                                                       \
        float dx = q##K.x - x##K.x, dy = q##K.y - x##K.y;                                   \
        float dz = q##K.z - x##K.z, dw = q##K.w - x##K.w;                                   \
        p = fmaf(dx, dx, fmaf(dy, dy, fmaf(dz, dz, fmaf(dw, dw, p))));                      \
        f4u r;                                                                              \
        r.x = x##K.x + dx; r.y = x##K.y + dy; r.z = x##K.z + dz; r.w = x##K.w + dw;         \
        oq4[(K) * 64 + lane] = r;                                                           \
    }
    ST(0) ST(1) ST(2) ST(3) ST(4) ST(5) ST(6) ST(7)
    ST(8) ST(9) ST(10) ST(11) ST(12) ST(13) ST(14) ST(15)
#undef ST
    for (int off = 32; off; off >>= 1) p += __shfl_xor(p, off);

    // one-hot row (O_ENC is 8B-aligned -> float2)
    float2* oe2 = (float2*)(out + O_ENC + (size_t)row * E_CODES);
#pragma unroll
    for (int k = 0; k < 4; k++) {
        const int e0 = (k * 64 + lane) * 2;
        float2 v; v.x = (e0 == beste) ? 1.0f : 0.0f; v.y = (e0 + 1 == beste) ? 1.0f : 0.0f;
        oe2[k * 64 + lane] = v;
    }

    // loss: block-level reduce, single spread-slot atomic per block
    if (lane == 0) {
        lred[w] = p;
        atomicAdd(&counts[beste], 1);   // 512 spread addresses — cheap
    }
    __syncthreads();
    if (tid == 0) {
        float P = ((lred[0] + lred[1]) + lred[2]) + lred[3];
        atomicAdd(&lossp[blockIdx.x & 511], P);
    }
}

// ---------------- loss + perplexity ----------------
__global__ __launch_bounds__(512) void k_final(const int* __restrict__ counts, const float* __restrict__ lossp,
                                               float* __restrict__ out) {
    const int tid = threadIdx.x;
    const int lane = tid & 63, w = tid >> 6;
    __shared__ float r[8];
    __shared__ float r2[8];
    const float p = (float)counts[tid] * (1.0f / 8192.0f);
    float h = p * logf(p + 1e-10f);
    float l = lossp[tid];
    for (int off = 32; off; off >>= 1) { h += __shfl_down(h, off); l += __shfl_down(l, off); }
    if (lane == 0) { r[w] = h; r2[w] = l; }
    __syncthreads();
    if (tid == 0) {
        float H = 0.f, L = 0.f;
        for (int k = 0; k < 8; k++) { H += r[k]; L += r2[k]; }
        out[O_PERP] = expf(-H);
        out[O_LOSS] = L * (1.25f / 33554432.0f);  // q_latent + 0.25*e_latent = 1.25*MSE
    }
}

extern "C" void kernel_launch(void* const* d_in, const int* in_sizes, int n_in,
                              void* d_out, int out_size, void* d_ws, size_t ws_size,
                              hipStream_t stream) {
    const float* X  = (const float*)d_in[0];   // inputs  [8192, 8,8,8,8] -> [8192,4096]
    const float* CB = (const float*)d_in[1];   // codebook [512, 4096]
    float* out = (float*)d_out;
    float* ws  = (float*)d_ws;
    float* scores = ws + WS_SCORES;
    float* enorm  = ws + WS_ENORM;   // doubles as lossp after k_gemm
    int*   counts = (int*)(ws + WS_COUNTS);
    ushort_t* cbbf = (ushort_t*)(out + O_CBBF);

    hipMemsetAsync(counts, 0, E_CODES * sizeof(int), stream);

    k_enorm<<<E_CODES, 64, 0, stream>>>(CB, enorm, cbbf);
    k_gemm<<<512, 256, 0, stream>>>(X, cbbf, enorm, scores);
    // enorm's job is done; zero it and reuse as 512 loss partial slots
    hipMemsetAsync(enorm, 0, E_CODES * sizeof(float), stream);
    k_fused<<<B_ROWS / 4, 256, 0, stream>>>(X, CB, scores, counts, enorm, out);
    k_final<<<1, 512, 0, stream>>>(counts, enorm, out);
}

// Round 12
// 377.496 us; speedup vs baseline: 1.0264x; 1.0264x over previous
//
#include <hip/hip_runtime.h>
#include <stdint.h>

#define B_ROWS 8192
#define DIM 4096
#define E_CODES 512
#define MARGIN 16.0f

typedef __attribute__((ext_vector_type(8))) short short8;
typedef __attribute__((ext_vector_type(4))) float floatx4;
typedef __attribute__((ext_vector_type(4), aligned(4))) float f4u;  // unaligned-ok float4
typedef unsigned short ushort_t;

// ---- workspace layout (float units) ----
#define WS_SCORES 0                       // final scores: 8192*512 floats
#define WS_ENORM  4194304                 // 512 floats: ||e||^2 for k_gemm, then ZEROED and
                                          // reused as 512 loss partial-sum slots for k_fused
#define WS_COUNTS 4194816                 // 512 ints

// ---- output layout (float units) ----
#define O_LOSS 0
#define O_Q    1
#define O_PERP 33554433
#define O_ENC  33554434
// scratch carved out of the Q region (fully overwritten by k_fused afterwards):
#define O_XBF   4          // bf16 X (swizzled): [4, 16777220)
#define O_CBBF  20971528   // bf16 CB (swizzled): [20971528, 22020104)

#define AS1 __attribute__((address_space(1)))
#define AS3 __attribute__((address_space(3)))

__device__ __forceinline__ void gld_lds16(const void* g, void* l) {
    // async global->LDS, 16B per lane; LDS dest = wave-uniform base + lane*16
    __builtin_amdgcn_global_load_lds((AS1 const void*)g, (AS3 void*)l, 16, 0, 0);
}

// pack two fp32 into (bf16(hi)<<16)|bf16(lo) by truncation — one v_perm_b32
__device__ inline uint32_t pk2(float hi, float lo) {
    return __builtin_amdgcn_perm(__float_as_uint(hi), __float_as_uint(lo), 0x07060302u);
}

// ---------------- codebook norms (fp32) ----------------
__global__ __launch_bounds__(64) void k_enorm(const float* __restrict__ cb, float* __restrict__ enorm) {
    const int e = blockIdx.x;
    const int lane = threadIdx.x;
    const float4* c4 = (const float4*)(cb + (size_t)e * DIM);
    float p = 0.f;
#pragma unroll
    for (int j = 0; j < 16; j++) {
        float4 v = c4[j * 64 + lane];
        p = fmaf(v.x, v.x, fmaf(v.y, v.y, fmaf(v.z, v.z, fmaf(v.w, v.w, p))));
    }
    for (int off = 32; off; off >>= 1) p += __shfl_down(p, off);
    if (lane == 0) enorm[e] = p;
}

// ---------------- bf16 pack with per-row XOR swizzle ----------------
// Within each 64-elem K-block, 16B-chunk c of row r is stored at chunk (c ^ (r&7)).
// Block-partitioned: blocks [0,2048) pack X (2048 chunks each), [2048,2176) pack CB.
__global__ __launch_bounds__(256) void k_pack(const float* __restrict__ X, const float* __restrict__ CB,
                                              ushort_t* __restrict__ xbf, ushort_t* __restrict__ cbbf) {
    const int b = blockIdx.x;
    const float* src;
    ushort_t* dst;
    int c0;
    if (b < 2048) { src = X;  dst = xbf;  c0 = b * 2048; }
    else          { src = CB; dst = cbbf; c0 = (b - 2048) * 2048; }
#pragma unroll
    for (int it = 0; it < 8; it++) {
        const int c = c0 + it * 256 + threadIdx.x;
        const int r = c >> 9, g = c & 511;
        const int gs = (g & ~7) | ((g & 7) ^ (r & 7));
        const float4* s4 = (const float4*)(src + ((size_t)c << 3));
        float4 v0 = s4[0], v1 = s4[1];
        *(uint4*)(dst + (size_t)r * DIM + gs * 8) =
            make_uint4(pk2(v0.y, v0.x), pk2(v0.w, v0.z), pk2(v1.y, v1.x), pk2(v1.w, v1.z));
    }
}

// ---------------- bf16 score GEMM: BM=64, BN=128, BK=64, counted-vmcnt 2-deep pipeline ------------
// XCD-AWARE MAPPING (the round-11 fix): x = bid&7 is the XCD (round-robin dispatch); each XCD
// owns 16 whole bm-panels (all 4 bn-blocks of a panel co-resident on the same XCD's L2), so
// every A-panel is fetched from HBM exactly once. cbbf (4 MB) re-reads are L2/L3-served.
__global__ __launch_bounds__(256, 2) void k_gemm(const ushort_t* __restrict__ xbf, const ushort_t* __restrict__ cbbf,
                                                 const float* __restrict__ enorm, float* __restrict__ scores) {
    __shared__ __align__(16) ushort_t As[3 * 64 * 64];    // 3 x 8 KiB
    __shared__ __align__(16) ushort_t Bs[3 * 128 * 64];   // 3 x 16 KiB
    const int bid = blockIdx.x;
    const int x = bid & 7;            // XCD id
    const int j = bid >> 3;           // 0..63 within XCD
    const int bm = x * 16 + (j >> 2); // 16 bm-panels per XCD
    const int bn = j & 3;
    const int tid = threadIdx.x;
    const int lane = tid & 63;
    const int w = tid >> 6;
    const int wr = w >> 1, wc = w & 1;
    const int m16 = lane & 15, q4 = lane >> 4;

    const int srow = lane >> 3;
    const int scol = (lane & 7) * 8;
    const ushort_t* ax = xbf + (size_t)(bm * 64 + w * 8 + srow) * DIM + scol;
    const ushort_t* bx = cbbf + (size_t)(bn * 128 + w * 8 + srow) * DIM + scol;

    floatx4 acc[2][4];
#pragma unroll
    for (int i = 0; i < 2; i++)
#pragma unroll
        for (int j2 = 0; j2 < 4; j2++) acc[i][j2] = (floatx4){0.f, 0.f, 0.f, 0.f};

    const int kx = (m16 & 7) * 8;  // frag-read XOR key (ushort units)

    // 6 gld_lds per wave per tile (2 A + 4 B) -> vmcnt granularity of 6
#define STAGE(BUF, KT)                                                                      \
    {                                                                                       \
        ushort_t* asd = &As[(BUF) * 4096];                                                  \
        ushort_t* bsd = &Bs[(BUF) * 8192];                                                  \
        _Pragma("unroll")                                                                   \
        for (int jj = 0; jj < 2; jj++)                                                      \
            gld_lds16(ax + (size_t)jj * 32 * DIM + (KT), asd + (jj * 32 + w * 8) * 64);     \
        _Pragma("unroll")                                                                   \
        for (int jj = 0; jj < 4; jj++)                                                      \
            gld_lds16(bx + (size_t)jj * 32 * DIM + (KT), bsd + (jj * 32 + w * 8) * 64);     \
    }

    STAGE(0, 0)
    STAGE(1, 64)
    int b0 = 0, b1 = 1, b2 = 2;

    for (int t = 0; t < 64; ++t) {
        // retire tile t's own 6 loads; keep t+1/t+2's in flight (never drain to 0 mid-loop)
        if (t < 63) asm volatile("s_waitcnt vmcnt(6)" ::: "memory");
        else        asm volatile("s_waitcnt vmcnt(0)" ::: "memory");
        __builtin_amdgcn_s_barrier();        // raw barrier: no compiler-forced vmcnt(0) drain
        __builtin_amdgcn_sched_barrier(0);   // rule #18: pin ds_reads below the barrier

        if (t + 2 < 64) STAGE(b2, (t + 2) * 64)

        const ushort_t* Ab = &As[b0 * 4096];
        const ushort_t* Bb = &Bs[b0 * 8192];
#pragma unroll
        for (int kk = 0; kk < 2; kk++) {
            short8 a[2], b[4];
#pragma unroll
            for (int i = 0; i < 2; i++)
                a[i] = *(const short8*)(&Ab[(wr * 32 + i * 16 + m16) * 64 + ((kk * 32 + q4 * 8) ^ kx)]);
#pragma unroll
            for (int j2 = 0; j2 < 4; j2++)
                b[j2] = *(const short8*)(&Bb[(wc * 64 + j2 * 16 + m16) * 64 + ((kk * 32 + q4 * 8) ^ kx)]);
#pragma unroll
            for (int i = 0; i < 2; i++)
#pragma unroll
                for (int j2 = 0; j2 < 4; j2++)
                    acc[i][j2] = __builtin_amdgcn_mfma_f32_16x16x32_bf16(a[i], b[j2], acc[i][j2], 0, 0, 0);
        }
        __builtin_amdgcn_sched_barrier(0);   // keep this tile's ds_reads inside its phase
        const int tmp = b0; b0 = b1; b1 = b2; b2 = tmp;
    }
#undef STAGE

    // epilogue: score = ||e||^2 - 2*dot ; C/D layout: col=lane&15, row=(lane>>4)*4+rr
#pragma unroll
    for (int j2 = 0; j2 < 4; j2++) {
        const int col = bn * 128 + wc * 64 + j2 * 16 + m16;
        const float en = enorm[col];
#pragma unroll
        for (int i = 0; i < 2; i++) {
            const int row0 = bm * 64 + wr * 32 + i * 16 + q4 * 4;
#pragma unroll
            for (int rr = 0; rr < 4; rr++)
                scores[(size_t)(row0 + rr) * E_CODES + col] = fmaf(-2.0f, acc[i][j2][rr], en);
        }
    }
}

// ---------------- fused: argmin + (rare) exact refine + quantize + one-hot + loss ----------------
// X-row prefetch issued BEFORE the argmin phase and pinned with sched_barrier(0) (round-8 win).
__global__ __launch_bounds__(256) void k_fused(const float* __restrict__ X, const float* __restrict__ CB,
                                               const float* __restrict__ scores,
                                               int* __restrict__ counts, float* __restrict__ lossp,
                                               float* __restrict__ out) {
    __shared__ float lred[4];
    const int tid = threadIdx.x;
    const int lane = tid & 63, w = tid >> 6;
    const int row = blockIdx.x * 4 + w;

    // phase 0a: issue score loads
    const float* sr = scores + (size_t)row * E_CODES;
    float s[8];
#pragma unroll
    for (int g = 0; g < 8; g++) s[g] = sr[g * 64 + lane];
    __builtin_amdgcn_sched_barrier(0);   // scores issued first (argmin waits only on these)

    // phase 0b: issue the full X row as 16 named float4 loads — independent of argmin
    const float4* xr4 = (const float4*)(X + (size_t)row * DIM);
#define LDX(K) float4 x##K = xr4[(K) * 64 + lane];
    LDX(0) LDX(1) LDX(2) LDX(3) LDX(4) LDX(5) LDX(6) LDX(7)
    LDX(8) LDX(9) LDX(10) LDX(11) LDX(12) LDX(13) LDX(14) LDX(15)
#undef LDX
    __builtin_amdgcn_sched_barrier(0);   // pin: X loads may NOT sink below this point

    // phase 1: wave argmin (approx scores), tie -> lower index
    float mv = s[0]; int mi = lane;
#pragma unroll
    for (int g = 1; g < 8; g++) { if (s[g] < mv) { mv = s[g]; mi = g * 64 + lane; } }
    for (int off = 32; off; off >>= 1) {
        float ov = __shfl_xor(mv, off); int oi = __shfl_xor(mi, off);
        if (ov < mv || (ov == mv && oi < mi)) { mv = ov; mi = oi; }
    }
    const float thr = mv + MARGIN;

    unsigned long long m0 = __ballot(s[0] <= thr), m1 = __ballot(s[1] <= thr);
    unsigned long long m2 = __ballot(s[2] <= thr), m3 = __ballot(s[3] <= thr);
    unsigned long long m4 = __ballot(s[4] <= thr), m5 = __ballot(s[5] <= thr);
    unsigned long long m6 = __ballot(s[6] <= thr), m7 = __ballot(s[7] <= thr);
    const int ncand = __popcll(m0) + __popcll(m1) + __popcll(m2) + __popcll(m3) +
                      __popcll(m4) + __popcll(m5) + __popcll(m6) + __popcll(m7);

    int beste = mi;  // unique candidate == approx argmin

    if (ncand > 1) {
        // exact fp32 refine over margin candidates; butterfly sums bit-identical on all lanes
        float bestd = 3.0e38f; beste = 1 << 30;
#define REFINE_GROUP(MG, G)                                                                 \
        {                                                                                   \
            unsigned long long mask = (MG);                                                 \
            while (mask) {                                                                  \
                const int b = __builtin_ctzll(mask); mask &= mask - 1;                      \
                const int e = (G) * 64 + b;                                                 \
                const float4* cr4 = (const float4*)(CB + (size_t)e * DIM);                  \
                float p = 0.f;                                                              \
                _Pragma("unroll")                                                           \
                for (int i = 0; i < 16; i++) {                                              \
                    float4 c = cr4[i * 64 + lane];                                          \
                    float4 x = xr4[i * 64 + lane];                                          \
                    float dx = x.x - c.x, dy = x.y - c.y, dz = x.z - c.z, dw = x.w - c.w;   \
                    p = fmaf(dx, dx, fmaf(dy, dy, fmaf(dz, dz, fmaf(dw, dw, p))));          \
                }                                                                           \
                for (int off = 32; off; off >>= 1) p += __shfl_xor(p, off);                 \
                if (p < bestd || (p == bestd && e < beste)) { bestd = p; beste = e; }       \
            }                                                                               \
        }
        REFINE_GROUP(m0, 0) REFINE_GROUP(m1, 1) REFINE_GROUP(m2, 2) REFINE_GROUP(m3, 3)
        REFINE_GROUP(m4, 4) REFINE_GROUP(m5, 5) REFINE_GROUP(m6, 6) REFINE_GROUP(m7, 7)
#undef REFINE_GROUP
    }

    // phase 2: quantized_st = x + (q - x); loss fma-nest i=0..15 + butterfly (bitwise as before).
    const float4* cq4 = (const float4*)(CB + (size_t)beste * DIM);
    f4u* oq4 = (f4u*)(out + O_Q + (size_t)row * DIM);   // out+1 is only 4B-aligned

#define LDQ(K) float4 q##K = cq4[(K) * 64 + lane];
    LDQ(0) LDQ(1) LDQ(2) LDQ(3) LDQ(4) LDQ(5) LDQ(6) LDQ(7)
    LDQ(8) LDQ(9) LDQ(10) LDQ(11) LDQ(12) LDQ(13) LDQ(14) LDQ(15)
#undef LDQ
    float p = 0.f;
#define ST(K)                                                                               \
    {                                                                                       \
        float dx = q##K.x - x##K.x, dy = q##K.y - x##K.y;                                   \
        float dz = q##K.z - x##K.z, dw = q##K.w - x##K.w;                                   \
        p = fmaf(dx, dx, fmaf(dy, dy, fmaf(dz, dz, fmaf(dw, dw, p))));                      \
        f4u r;                                                                              \
        r.x = x##K.x + dx; r.y = x##K.y + dy; r.z = x##K.z + dz; r.w = x##K.w + dw;         \
        oq4[(K) * 64 + lane] = r;                                                           \
    }
    ST(0) ST(1) ST(2) ST(3) ST(4) ST(5) ST(6) ST(7)
    ST(8) ST(9) ST(10) ST(11) ST(12) ST(13) ST(14) ST(15)
#undef ST
    for (int off = 32; off; off >>= 1) p += __shfl_xor(p, off);

    // one-hot row (O_ENC is 8B-aligned -> float2)
    float2* oe2 = (float2*)(out + O_ENC + (size_t)row * E_CODES);
#pragma unroll
    for (int k = 0; k < 4; k++) {
        const int e0 = (k * 64 + lane) * 2;
        float2 v; v.x = (e0 == beste) ? 1.0f : 0.0f; v.y = (e0 + 1 == beste) ? 1.0f : 0.0f;
        oe2[k * 64 + lane] = v;
    }

    // loss: block-level reduce, single spread-slot atomic per block
    if (lane == 0) {
        lred[w] = p;
        atomicAdd(&counts[beste], 1);   // 512 spread addresses — cheap
    }
    __syncthreads();
    if (tid == 0) {
        float P = ((lred[0] + lred[1]) + lred[2]) + lred[3];
        atomicAdd(&lossp[blockIdx.x & 511], P);
    }
}

// ---------------- loss + perplexity ----------------
__global__ __launch_bounds__(512) void k_final(const int* __restrict__ counts, const float* __restrict__ lossp,
                                               float* __restrict__ out) {
    const int tid = threadIdx.x;
    const int lane = tid & 63, w = tid >> 6;
    __shared__ float r[8];
    __shared__ float r2[8];
    const float p = (float)counts[tid] * (1.0f / 8192.0f);
    float h = p * logf(p + 1e-10f);
    float l = lossp[tid];
    for (int off = 32; off; off >>= 1) { h += __shfl_down(h, off); l += __shfl_down(l, off); }
    if (lane == 0) { r[w] = h; r2[w] = l; }
    __syncthreads();
    if (tid == 0) {
        float H = 0.f, L = 0.f;
        for (int k = 0; k < 8; k++) { H += r[k]; L += r2[k]; }
        out[O_PERP] = expf(-H);
        out[O_LOSS] = L * (1.25f / 33554432.0f);  // q_latent + 0.25*e_latent = 1.25*MSE
    }
}

extern "C" void kernel_launch(void* const* d_in, const int* in_sizes, int n_in,
                              void* d_out, int out_size, void* d_ws, size_t ws_size,
                              hipStream_t stream) {
    const float* X  = (const float*)d_in[0];   // inputs  [8192, 8,8,8,8] -> [8192,4096]
    const float* CB = (const float*)d_in[1];   // codebook [512, 4096]
    float* out = (float*)d_out;
    float* ws  = (float*)d_ws;
    float* scores = ws + WS_SCORES;
    float* enorm  = ws + WS_ENORM;   // doubles as lossp after k_gemm
    int*   counts = (int*)(ws + WS_COUNTS);
    ushort_t* xbf  = (ushort_t*)(out + O_XBF);
    ushort_t* cbbf = (ushort_t*)(out + O_CBBF);

    hipMemsetAsync(counts, 0, E_CODES * sizeof(int), stream);

    k_pack<<<2176, 256, 0, stream>>>(X, CB, xbf, cbbf);
    k_enorm<<<E_CODES, 64, 0, stream>>>(CB, enorm);
    k_gemm<<<512, 256, 0, stream>>>(xbf, cbbf, enorm, scores);
    // enorm's job is done; zero it and reuse as 512 loss partial slots
    hipMemsetAsync(enorm, 0, E_CODES * sizeof(float), stream);
    k_fused<<<B_ROWS / 4, 256, 0, stream>>>(X, CB, scores, counts, enorm, out);
    k_final<<<1, 512, 0, stream>>>(counts, enorm, out);
}

// Round 13
// 368.714 us; speedup vs baseline: 1.0509x; 1.0238x over previous
//
#include <hip/hip_runtime.h>
#include <stdint.h>

#define B_ROWS 8192
#define DIM 4096
#define E_CODES 512
#define MARGIN 16.0f

typedef __attribute__((ext_vector_type(8))) short short8;
typedef __attribute__((ext_vector_type(4))) float floatx4;
typedef __attribute__((ext_vector_type(4), aligned(4))) float f4u;  // unaligned-ok float4
typedef unsigned short ushort_t;

// ---- workspace layout (float units) ----
#define WS_SCORES 0                       // final scores: 8192*512 floats
#define WS_ENORM  4194304                 // 512 floats: ||e||^2 for k_gemm, then ZEROED and
                                          // reused as 512 loss partial-sum slots for k_fused
#define WS_COUNTS 4194816                 // 512 ints

// ---- output layout (float units) ----
#define O_LOSS 0
#define O_Q    1
#define O_PERP 33554433
#define O_ENC  33554434
// scratch carved out of the Q region (fully overwritten by k_fused afterwards):
#define O_CBBF  20971528   // bf16 CB (swizzled): [20971528, 22020104)

#define AS1 __attribute__((address_space(1)))
#define AS3 __attribute__((address_space(3)))

__device__ __forceinline__ void gld_lds16(const void* g, void* l) {
    // async global->LDS, 16B per lane; LDS dest = wave-uniform base + lane*16
    __builtin_amdgcn_global_load_lds((AS1 const void*)g, (AS3 void*)l, 16, 0, 0);
}

// pack two fp32 into (bf16(hi)<<16)|bf16(lo) by truncation — one v_perm_b32
__device__ inline uint32_t pk2(float hi, float lo) {
    return __builtin_amdgcn_perm(__float_as_uint(hi), __float_as_uint(lo), 0x07060302u);
}

// ---------------- codebook norms + bf16 pack (swizzled) ----------------
// Pack swizzle: within each 64-elem K-block, 16B-chunk g&7 of row e stored at ((g&7)^(e&7)).
__global__ __launch_bounds__(64) void k_enorm(const float* __restrict__ cb, float* __restrict__ enorm,
                                              ushort_t* __restrict__ cbbf) {
    const int e = blockIdx.x;
    const int lane = threadIdx.x;
    const float4* c4 = (const float4*)(cb + (size_t)e * DIM);
    float p = 0.f;
#pragma unroll
    for (int j = 0; j < 16; j++) {
        float4 v = c4[j * 64 + lane];
        p = fmaf(v.x, v.x, fmaf(v.y, v.y, fmaf(v.z, v.z, fmaf(v.w, v.w, p))));
    }
    for (int off = 32; off; off >>= 1) p += __shfl_down(p, off);
    if (lane == 0) enorm[e] = p;
    // pack this row (reads are L1-hot from the norm pass)
#pragma unroll
    for (int k = 0; k < 8; k++) {
        const int g = k * 64 + lane;
        const int gs = (g & ~7) | ((g & 7) ^ (e & 7));
        float4 v0 = c4[2 * g], v1 = c4[2 * g + 1];
        *(uint4*)(cbbf + (size_t)e * DIM + gs * 8) =
            make_uint4(pk2(v0.y, v0.x), pk2(v0.w, v0.z), pk2(v1.y, v1.x), pk2(v1.w, v1.z));
    }
}

// ---------------- bf16 score GEMM: BM=64, BN=128, BK=64, counted-vmcnt 2-deep pipeline ------------
// A staged DIRECTLY from fp32 X (global->reg->pk2->swizzled ds_write); B via global_load_lds
// from pre-swizzled cbbf. XCD-aware mapping (round-12 win): each XCD owns 16 whole bm-panels,
// so every X panel is fetched from HBM once and its 4 bn-readers hit L2.
// 8 VMEM ops/wave/iter -> vmcnt(8) retires exactly the previous iteration's batch.
__global__ __launch_bounds__(256, 2) void k_gemm(const float* __restrict__ X, const ushort_t* __restrict__ cbbf,
                                                 const float* __restrict__ enorm, float* __restrict__ scores) {
    __shared__ __align__(16) ushort_t As[3 * 64 * 64];    // 3 x 8 KiB
    __shared__ __align__(16) ushort_t Bs[3 * 128 * 64];   // 3 x 16 KiB
    const int bid = blockIdx.x;
    const int xcd = bid & 7;              // XCD id (round-robin dispatch)
    const int jb = bid >> 3;              // 0..63 within XCD
    const int bm = xcd * 16 + (jb >> 2);  // 16 bm-panels per XCD
    const int bn = jb & 3;
    const int tid = threadIdx.x;
    const int lane = tid & 63;
    const int w = tid >> 6;
    const int wr = w >> 1, wc = w & 1;
    const int m16 = lane & 15, q4 = lane >> 4;

    // B staging: lane l covers (row l>>3, 16B chunk l&7) of an 8-row stripe
    const int srow = lane >> 3;
    const int scol = (lane & 7) * 8;
    const ushort_t* bx = cbbf + (size_t)(bn * 128 + w * 8 + srow) * DIM + scol;

    // A reg-staging: lane l covers row w*16 + (l>>2), fp32 cols (l&3)*16 .. +16 of the K-tile
    const int arow = w * 16 + (lane >> 2);
    const float4* axf = (const float4*)(X + (size_t)(bm * 64 + arow) * DIM + (lane & 3) * 16);
    const int c0 = (lane & 3) * 2;
    const int sfx = arow & 7;
    const int apos1 = ((c0) ^ sfx) * 8;
    const int apos2 = ((c0 + 1) ^ sfx) * 8;

    floatx4 acc[2][4];
#pragma unroll
    for (int i = 0; i < 2; i++)
#pragma unroll
        for (int j = 0; j < 4; j++) acc[i][j] = (floatx4){0.f, 0.f, 0.f, 0.f};

    const int kx = (m16 & 7) * 8;  // frag-read XOR key (ushort units); matches arow&7

#define STAGE_B(BUF, KT)                                                                    \
    {                                                                                       \
        ushort_t* bsd = &Bs[(BUF) * 8192];                                                  \
        _Pragma("unroll")                                                                   \
        for (int jj = 0; jj < 4; jj++)                                                      \
            gld_lds16(bx + (size_t)jj * 32 * DIM + (KT), bsd + (jj * 32 + w * 8) * 64);     \
    }
#define LOADA(P, KT)                                                                        \
    { const float4* s_ = axf + ((KT) >> 2); P##0 = s_[0]; P##1 = s_[1]; P##2 = s_[2]; P##3 = s_[3]; }
#define PACKA(P, BUF)                                                                       \
    {                                                                                       \
        *(uint4*)(&As[(BUF) * 4096 + arow * 64 + apos1]) =                                  \
            make_uint4(pk2((P##0).y, (P##0).x), pk2((P##0).w, (P##0).z),                    \
                       pk2((P##1).y, (P##1).x), pk2((P##1).w, (P##1).z));                   \
        *(uint4*)(&As[(BUF) * 4096 + arow * 64 + apos2]) =                                  \
            make_uint4(pk2((P##2).y, (P##2).x), pk2((P##2).w, (P##2).z),                    \
                       pk2((P##3).y, (P##3).x), pk2((P##3).w, (P##3).z));                   \
    }
#define COMPUTE(BUF)                                                                        \
    {                                                                                       \
        const ushort_t* Ab = &As[(BUF) * 4096];                                             \
        const ushort_t* Bb = &Bs[(BUF) * 8192];                                             \
        _Pragma("unroll")                                                                   \
        for (int kk = 0; kk < 2; kk++) {                                                    \
            short8 a[2], b[4];                                                              \
            _Pragma("unroll")                                                               \
            for (int i = 0; i < 2; i++)                                                     \
                a[i] = *(const short8*)(&Ab[(wr * 32 + i * 16 + m16) * 64 + ((kk * 32 + q4 * 8) ^ kx)]); \
            _Pragma("unroll")                                                               \
            for (int j = 0; j < 4; j++)                                                     \
                b[j] = *(const short8*)(&Bb[(wc * 64 + j * 16 + m16) * 64 + ((kk * 32 + q4 * 8) ^ kx)]); \
            _Pragma("unroll")                                                               \
            for (int i = 0; i < 2; i++)                                                     \
                _Pragma("unroll")                                                           \
                for (int j = 0; j < 4; j++)                                                 \
                    acc[i][j] = __builtin_amdgcn_mfma_f32_16x16x32_bf16(a[i], b[j], acc[i][j], 0, 0, 0); \
        }                                                                                   \
    }
#define TOPBAR                                                                              \
    asm volatile("s_waitcnt lgkmcnt(0)" ::: "memory");                                      \
    __builtin_amdgcn_s_barrier();                                                           \
    __builtin_amdgcn_sched_barrier(0);
#define ROT { const int tmp_ = b0; b0 = b1; b1 = b2; b2 = tmp_; }

    float4 rA0, rA1, rA2, rA3, rB0, rB1, rB2, rB3;

    // prologue: tiles 0,1 in flight; pack tile0 (own-wave writes; barrier at loop top publishes)
    STAGE_B(0, 0)   LOADA(rA, 0)
    STAGE_B(1, 64)  LOADA(rB, 64)
    asm volatile("s_waitcnt vmcnt(8)" ::: "memory");   // batch 0 retired
    PACKA(rA, 0)
    int b0 = 0, b1 = 1, b2 = 2;

    for (int t = 0; t < 62; t += 2) {
        // sub-iter t (computes tile t, packs tile t+1 from rB, loads tile t+2 into rA)
        TOPBAR
        STAGE_B(b2, (t + 2) * 64)  LOADA(rA, (t + 2) * 64)
        COMPUTE(b0)
        asm volatile("s_waitcnt vmcnt(8)" ::: "memory");   // previous batch retired -> rB valid
        PACKA(rB, b1)
        __builtin_amdgcn_sched_barrier(0);
        ROT
        // sub-iter t+1 (computes t+1, packs t+2 from rA, loads t+3 into rB)
        TOPBAR
        STAGE_B(b2, (t + 3) * 64)  LOADA(rB, (t + 3) * 64)
        COMPUTE(b0)
        asm volatile("s_waitcnt vmcnt(8)" ::: "memory");
        PACKA(rA, b1)
        __builtin_amdgcn_sched_barrier(0);
        ROT
    }
    // t = 62: compute 62, pack tile 63 from rB (loaded at t=61)
    TOPBAR
    COMPUTE(b0)
    asm volatile("s_waitcnt vmcnt(0)" ::: "memory");
    PACKA(rB, b1)
    __builtin_amdgcn_sched_barrier(0);
    ROT
    // t = 63
    TOPBAR
    COMPUTE(b0)
#undef STAGE_B
#undef LOADA
#undef PACKA
#undef COMPUTE
#undef TOPBAR
#undef ROT

    // epilogue: score = ||e||^2 - 2*dot ; C/D layout: col=lane&15, row=(lane>>4)*4+rr
#pragma unroll
    for (int j = 0; j < 4; j++) {
        const int col = bn * 128 + wc * 64 + j * 16 + m16;
        const float en = enorm[col];
#pragma unroll
        for (int i = 0; i < 2; i++) {
            const int row0 = bm * 64 + wr * 32 + i * 16 + q4 * 4;
#pragma unroll
            for (int rr = 0; rr < 4; rr++)
                scores[(size_t)(row0 + rr) * E_CODES + col] = fmaf(-2.0f, acc[i][j][rr], en);
        }
    }
}

// ---------------- fused: argmin + (rare) exact refine + quantize + one-hot + loss ----------------
// X-row prefetch issued BEFORE the argmin phase and pinned with sched_barrier(0) (round-8 win).
__global__ __launch_bounds__(256) void k_fused(const float* __restrict__ X, const float* __restrict__ CB,
                                               const float* __restrict__ scores,
                                               int* __restrict__ counts, float* __restrict__ lossp,
                                               float* __restrict__ out) {
    __shared__ float lred[4];
    const int tid = threadIdx.x;
    const int lane = tid & 63, w = tid >> 6;
    const int row = blockIdx.x * 4 + w;

    // phase 0a: issue score loads
    const float* sr = scores + (size_t)row * E_CODES;
    float s[8];
#pragma unroll
    for (int g = 0; g < 8; g++) s[g] = sr[g * 64 + lane];
    __builtin_amdgcn_sched_barrier(0);   // scores issued first (argmin waits only on these)

    // phase 0b: issue the full X row as 16 named float4 loads — independent of argmin
    const float4* xr4 = (const float4*)(X + (size_t)row * DIM);
#define LDX(K) float4 x##K = xr4[(K) * 64 + lane];
    LDX(0) LDX(1) LDX(2) LDX(3) LDX(4) LDX(5) LDX(6) LDX(7)
    LDX(8) LDX(9) LDX(10) LDX(11) LDX(12) LDX(13) LDX(14) LDX(15)
#undef LDX
    __builtin_amdgcn_sched_barrier(0);   // pin: X loads may NOT sink below this point

    // phase 1: wave argmin (approx scores), tie -> lower index
    float mv = s[0]; int mi = lane;
#pragma unroll
    for (int g = 1; g < 8; g++) { if (s[g] < mv) { mv = s[g]; mi = g * 64 + lane; } }
    for (int off = 32; off; off >>= 1) {
        float ov = __shfl_xor(mv, off); int oi = __shfl_xor(mi, off);
        if (ov < mv || (ov == mv && oi < mi)) { mv = ov; mi = oi; }
    }
    const float thr = mv + MARGIN;

    unsigned long long m0 = __ballot(s[0] <= thr), m1 = __ballot(s[1] <= thr);
    unsigned long long m2 = __ballot(s[2] <= thr), m3 = __ballot(s[3] <= thr);
    unsigned long long m4 = __ballot(s[4] <= thr), m5 = __ballot(s[5] <= thr);
    unsigned long long m6 = __ballot(s[6] <= thr), m7 = __ballot(s[7] <= thr);
    const int ncand = __popcll(m0) + __popcll(m1) + __popcll(m2) + __popcll(m3) +
                      __popcll(m4) + __popcll(m5) + __popcll(m6) + __popcll(m7);

    int beste = mi;  // unique candidate == approx argmin

    if (ncand > 1) {
        // exact fp32 refine over margin candidates; butterfly sums bit-identical on all lanes
        float bestd = 3.0e38f; beste = 1 << 30;
#define REFINE_GROUP(MG, G)                                                                 \
        {                                                                                   \
            unsigned long long mask = (MG);                                                 \
            while (mask) {                                                                  \
                const int b = __builtin_ctzll(mask); mask &= mask - 1;                      \
                const int e = (G) * 64 + b;                                                 \
                const float4* cr4 = (const float4*)(CB + (size_t)e * DIM);                  \
                float p = 0.f;                                                              \
                _Pragma("unroll")                                                           \
                for (int i = 0; i < 16; i++) {                                              \
                    float4 c = cr4[i * 64 + lane];                                          \
                    float4 x = xr4[i * 64 + lane];                                          \
                    float dx = x.x - c.x, dy = x.y - c.y, dz = x.z - c.z, dw = x.w - c.w;   \
                    p = fmaf(dx, dx, fmaf(dy, dy, fmaf(dz, dz, fmaf(dw, dw, p))));          \
                }                                                                           \
                for (int off = 32; off; off >>= 1) p += __shfl_xor(p, off);                 \
                if (p < bestd || (p == bestd && e < beste)) { bestd = p; beste = e; }       \
            }                                                                               \
        }
        REFINE_GROUP(m0, 0) REFINE_GROUP(m1, 1) REFINE_GROUP(m2, 2) REFINE_GROUP(m3, 3)
        REFINE_GROUP(m4, 4) REFINE_GROUP(m5, 5) REFINE_GROUP(m6, 6) REFINE_GROUP(m7, 7)
#undef REFINE_GROUP
    }

    // phase 2: quantized_st = x + (q - x); loss fma-nest i=0..15 + butterfly (bitwise as before).
    const float4* cq4 = (const float4*)(CB + (size_t)beste * DIM);
    f4u* oq4 = (f4u*)(out + O_Q + (size_t)row * DIM);   // out+1 is only 4B-aligned

#define LDQ(K) float4 q##K = cq4[(K) * 64 + lane];
    LDQ(0) LDQ(1) LDQ(2) LDQ(3) LDQ(4) LDQ(5) LDQ(6) LDQ(7)
    LDQ(8) LDQ(9) LDQ(10) LDQ(11) LDQ(12) LDQ(13) LDQ(14) LDQ(15)
#undef LDQ
    float p = 0.f;
#define ST(K)                                                                               \
    {                                                                                       \
        float dx = q##K.x - x##K.x, dy = q##K.y - x##K.y;                                   \
        float dz = q##K.z - x##K.z, dw = q##K.w - x##K.w;                                   \
        p = fmaf(dx, dx, fmaf(dy, dy, fmaf(dz, dz, fmaf(dw, dw, p))));                      \
        f4u r;                                                                              \
        r.x = x##K.x + dx; r.y = x##K.y + dy; r.z = x##K.z + dz; r.w = x##K.w + dw;         \
        oq4[(K) * 64 + lane] = r;                                                           \
    }
    ST(0) ST(1) ST(2) ST(3) ST(4) ST(5) ST(6) ST(7)
    ST(8) ST(9) ST(10) ST(11) ST(12) ST(13) ST(14) ST(15)
#undef ST
    for (int off = 32; off; off >>= 1) p += __shfl_xor(p, off);

    // one-hot row (O_ENC is 8B-aligned -> float2)
    float2* oe2 = (float2*)(out + O_ENC + (size_t)row * E_CODES);
#pragma unroll
    for (int k = 0; k < 4; k++) {
        const int e0 = (k * 64 + lane) * 2;
        float2 v; v.x = (e0 == beste) ? 1.0f : 0.0f; v.y = (e0 + 1 == beste) ? 1.0f : 0.0f;
        oe2[k * 64 + lane] = v;
    }

    // loss: block-level reduce, single spread-slot atomic per block
    if (lane == 0) {
        lred[w] = p;
        atomicAdd(&counts[beste], 1);   // 512 spread addresses — cheap
    }
    __syncthreads();
    if (tid == 0) {
        float P = ((lred[0] + lred[1]) + lred[2]) + lred[3];
        atomicAdd(&lossp[blockIdx.x & 511], P);
    }
}

// ---------------- loss + perplexity ----------------
__global__ __launch_bounds__(512) void k_final(const int* __restrict__ counts, const float* __restrict__ lossp,
                                               float* __restrict__ out) {
    const int tid = threadIdx.x;
    const int lane = tid & 63, w = tid >> 6;
    __shared__ float r[8];
    __shared__ float r2[8];
    const float p = (float)counts[tid] * (1.0f / 8192.0f);
    float h = p * logf(p + 1e-10f);
    float l = lossp[tid];
    for (int off = 32; off; off >>= 1) { h += __shfl_down(h, off); l += __shfl_down(l, off); }
    if (lane == 0) { r[w] = h; r2[w] = l; }
    __syncthreads();
    if (tid == 0) {
        float H = 0.f, L = 0.f;
        for (int k = 0; k < 8; k++) { H += r[k]; L += r2[k]; }
        out[O_PERP] = expf(-H);
        out[O_LOSS] = L * (1.25f / 33554432.0f);  // q_latent + 0.25*e_latent = 1.25*MSE
    }
}

extern "C" void kernel_launch(void* const* d_in, const int* in_sizes, int n_in,
                              void* d_out, int out_size, void* d_ws, size_t ws_size,
                              hipStream_t stream) {
    const float* X  = (const float*)d_in[0];   // inputs  [8192, 8,8,8,8] -> [8192,4096]
    const float* CB = (const float*)d_in[1];   // codebook [512, 4096]
    float* out = (float*)d_out;
    float* ws  = (float*)d_ws;
    float* scores = ws + WS_SCORES;
    float* enorm  = ws + WS_ENORM;   // doubles as lossp after k_gemm
    int*   counts = (int*)(ws + WS_COUNTS);
    ushort_t* cbbf = (ushort_t*)(out + O_CBBF);

    hipMemsetAsync(counts, 0, E_CODES * sizeof(int), stream);

    k_enorm<<<E_CODES, 64, 0, stream>>>(CB, enorm, cbbf);
    k_gemm<<<512, 256, 0, stream>>>(X, cbbf, enorm, scores);
    // enorm's job is done; zero it and reuse as 512 loss partial slots
    hipMemsetAsync(enorm, 0, E_CODES * sizeof(float), stream);
    k_fused<<<B_ROWS / 4, 256, 0, stream>>>(X, CB, scores, counts, enorm, out);
    k_final<<<1, 512, 0, stream>>>(counts, enorm, out);
}